// Round 1
// baseline (2281.418 us; speedup 1.0000x reference)
//
#include <hip/hip_runtime.h>
#include <hip/hip_bf16.h>

// Problem: B=4, S=2048, D=512, H=8, HD=64
#define B_ 4
#define S_ 2048
#define D_ 512
#define H_ 8
#define HD_ 64

typedef unsigned int uint;

__device__ __forceinline__ float bflo(uint u){ union{uint i;float f;}c; c.i = u<<16;          return c.f; }
__device__ __forceinline__ float bfhi(uint u){ union{uint i;float f;}c; c.i = u & 0xffff0000u; return c.f; }

// ---------------------------------------------------------------------------
// Kernel 1: fused QKV projection. C[row, e] = x[row,:] . W[e,:] + b[e]
// M=8192 (b*S+s), N=512 (e = h*64+d), K=512. Outputs bf16 in (B,H,S,HD).
// LDS tiles stored TRANSPOSED [k][m] / [k][n] -> outer-product inner loop:
// 2x ds_read_b128 per 16 FMAs, conflict-light.
// ---------------------------------------------------------------------------
__global__ __launch_bounds__(256) void qkv_gemm(
    const float* __restrict__ x,
    const float* __restrict__ Wq, const float* __restrict__ bq,
    const float* __restrict__ Wk, const float* __restrict__ bk,
    const float* __restrict__ Wv, const float* __restrict__ bv,
    __hip_bfloat16* __restrict__ Qb, __hip_bfloat16* __restrict__ Kb,
    __hip_bfloat16* __restrict__ Vb)
{
    __shared__ float As[64][68];  // [k][m]
    __shared__ float Bs[64][68];  // [k][n]
    const int which = blockIdx.z;
    const float* W    = which==0 ? Wq : (which==1 ? Wk : Wv);
    const float* bias = which==0 ? bq : (which==1 ? bk : bv);
    __hip_bfloat16* Out = which==0 ? Qb : (which==1 ? Kb : Vb);

    const int row0 = blockIdx.y * 64;
    const int col0 = blockIdx.x * 64;
    const int tid = threadIdx.x;
    const int tx = tid & 15, ty = tid >> 4;
    const int lr = tid >> 4, lc = tid & 15;

    float acc[4][4] = {};
    for (int k0 = 0; k0 < 512; k0 += 64) {
        #pragma unroll
        for (int i = 0; i < 4; ++i) {
            int r = lr + i * 16;
            float4 xa = *(const float4*)&x[(size_t)(row0 + r) * 512 + k0 + lc * 4];
            As[lc*4+0][r] = xa.x; As[lc*4+1][r] = xa.y;
            As[lc*4+2][r] = xa.z; As[lc*4+3][r] = xa.w;
            float4 wb = *(const float4*)&W[(size_t)(col0 + r) * 512 + k0 + lc * 4];
            Bs[lc*4+0][r] = wb.x; Bs[lc*4+1][r] = wb.y;
            Bs[lc*4+2][r] = wb.z; Bs[lc*4+3][r] = wb.w;
        }
        __syncthreads();
        #pragma unroll
        for (int kk = 0; kk < 64; ++kk) {
            float4 a4 = *(const float4*)&As[kk][ty*4];
            float4 b4 = *(const float4*)&Bs[kk][tx*4];
            float av[4] = {a4.x, a4.y, a4.z, a4.w};
            float bw[4] = {b4.x, b4.y, b4.z, b4.w};
            #pragma unroll
            for (int i = 0; i < 4; ++i)
                #pragma unroll
                for (int j = 0; j < 4; ++j)
                    acc[i][j] += av[i] * bw[j];
        }
        __syncthreads();
    }
    #pragma unroll
    for (int i = 0; i < 4; ++i) {
        int grow = row0 + ty*4 + i;
        int b = grow >> 11, s = grow & 2047;
        #pragma unroll
        for (int j = 0; j < 4; ++j) {
            int gcol = col0 + tx*4 + j;
            float v = acc[i][j] + bias[gcol];
            int h = gcol >> 6, d = gcol & 63;
            Out[(((size_t)(b*H_ + h) * S_ + s) << 6) + d] = __float2bfloat16(v);
        }
    }
}

// ---------------------------------------------------------------------------
// Kernel 2: Vsum[b,h,d] = sum_s V[b,h,s,d]   (docking blend sums over ALL keys)
// ---------------------------------------------------------------------------
__global__ __launch_bounds__(256) void vsum_kernel(
    const __hip_bfloat16* __restrict__ Vb, float* __restrict__ Vsum)
{
    int bh = blockIdx.x;          // 0..31
    int t = threadIdx.x;          // 256
    int d = t & 63, part = t >> 6;
    float s = 0.f;
    const __hip_bfloat16* vp = Vb + ((size_t)bh * S_) * HD_ + d;
    for (int si = part * 512; si < part * 512 + 512; ++si)
        s += __bfloat162float(vp[(size_t)si * HD_]);
    __shared__ float red[256];
    red[t] = s;
    __syncthreads();
    if (part == 0)
        Vsum[bh * 64 + d] = red[d] + red[64 + d] + red[128 + d] + red[192 + d];
}

// ---------------------------------------------------------------------------
// Kernel 3: flash attention, one q-row per thread, online softmax.
// ctx[b,s,h*64+d] = (1-beta) * softmax(QK^T/8 + keymask) V + beta*ds[b,q]*Vsum
// Masked scores use finite -1e30 sentinel (self-correcting, no NaNs).
// ---------------------------------------------------------------------------
__global__ __launch_bounds__(256, 1) void attn_kernel(
    const __hip_bfloat16* __restrict__ Qb, const __hip_bfloat16* __restrict__ Kb,
    const __hip_bfloat16* __restrict__ Vb, const float* __restrict__ Vsum,
    const float* __restrict__ dock, const int* __restrict__ mask,
    const float* __restrict__ beta_p, float* __restrict__ ctx)
{
    __shared__ float Ks[64][68];
    __shared__ float Vs[64][68];
    __shared__ float mb[64];
    const int bh = blockIdx.y;            // b*8+h
    const int b = bh >> 3, h = bh & 7;
    const int t = threadIdx.x;
    const int q = blockIdx.x * 256 + t;
    const float beta = beta_p[0];

    // Q row -> registers (fp32)
    float4 qv[16];
    {
        const uint* Qr = (const uint*)(Qb + (((size_t)bh * S_) + q) * HD_);
        #pragma unroll
        for (int d4 = 0; d4 < 16; ++d4) {
            uint2 u = ((const uint2*)Qr)[d4];
            qv[d4] = make_float4(bflo(u.x), bfhi(u.x), bflo(u.y), bfhi(u.y));
        }
    }

    float4 acc[16];
    #pragma unroll
    for (int i = 0; i < 16; ++i) acc[i] = make_float4(0.f, 0.f, 0.f, 0.f);
    float m = -1e30f, l = 0.f;

    for (int k0 = 0; k0 < S_; k0 += 64) {
        // stage K/V tile (bf16 -> fp32), rows padded to 68 floats
        for (int c = t; c < 512; c += 256) {
            int r = c >> 3, o8 = (c & 7) * 8;
            uint4 ku = *(const uint4*)(Kb + (((size_t)bh * S_) + k0 + r) * HD_ + o8);
            Ks[r][o8+0]=bflo(ku.x); Ks[r][o8+1]=bfhi(ku.x);
            Ks[r][o8+2]=bflo(ku.y); Ks[r][o8+3]=bfhi(ku.y);
            Ks[r][o8+4]=bflo(ku.z); Ks[r][o8+5]=bfhi(ku.z);
            Ks[r][o8+6]=bflo(ku.w); Ks[r][o8+7]=bfhi(ku.w);
            uint4 vu = *(const uint4*)(Vb + (((size_t)bh * S_) + k0 + r) * HD_ + o8);
            Vs[r][o8+0]=bflo(vu.x); Vs[r][o8+1]=bfhi(vu.x);
            Vs[r][o8+2]=bflo(vu.y); Vs[r][o8+3]=bfhi(vu.y);
            Vs[r][o8+4]=bflo(vu.z); Vs[r][o8+5]=bfhi(vu.z);
            Vs[r][o8+6]=bflo(vu.w); Vs[r][o8+7]=bfhi(vu.w);
        }
        if (t < 64) mb[t] = (mask[b * S_ + k0 + t] != 0) ? 0.f : -1e30f;
        __syncthreads();

        for (int chunk = 0; chunk < 4; ++chunk) {
            const int kb = chunk * 16;
            float sc[16];
            #pragma unroll
            for (int k = 0; k < 16; ++k) sc[k] = 0.f;
            #pragma unroll
            for (int d4 = 0; d4 < 16; ++d4) {
                float4 qq = qv[d4];
                #pragma unroll
                for (int k = 0; k < 16; ++k) {
                    float4 kv = *(const float4*)&Ks[kb + k][d4*4];
                    sc[k] += qq.x*kv.x + qq.y*kv.y + qq.z*kv.z + qq.w*kv.w;
                }
            }
            float tm = -1e30f;
            #pragma unroll
            for (int k = 0; k < 16; ++k) {
                sc[k] = sc[k] * 0.125f + mb[kb + k];
                tm = fmaxf(tm, sc[k]);
            }
            float mnew = fmaxf(m, tm);
            float f = __expf(m - mnew);
            l *= f;
            #pragma unroll
            for (int i = 0; i < 16; ++i) {
                acc[i].x *= f; acc[i].y *= f; acc[i].z *= f; acc[i].w *= f;
            }
            m = mnew;
            #pragma unroll
            for (int k = 0; k < 16; ++k) {
                float p = __expf(sc[k] - mnew);
                l += p;
                #pragma unroll
                for (int d4 = 0; d4 < 16; ++d4) {
                    float4 vv = *(const float4*)&Vs[kb + k][d4*4];
                    acc[d4].x += p*vv.x; acc[d4].y += p*vv.y;
                    acc[d4].z += p*vv.z; acc[d4].w += p*vv.w;
                }
            }
        }
        __syncthreads();
    }

    float dsq = (mask[b * S_ + q] != 0) ? dock[b * S_ + q] : 0.f;
    float w1 = (1.f - beta) / l;
    float w2 = beta * dsq;
    const float4* vs4 = (const float4*)(Vsum + bh * 64);
    float* cp = ctx + ((size_t)(b * S_ + q)) * D_ + h * HD_;
    #pragma unroll
    for (int d4 = 0; d4 < 16; ++d4) {
        float4 vsv = vs4[d4];
        float4 o;
        o.x = acc[d4].x*w1 + w2*vsv.x;
        o.y = acc[d4].y*w1 + w2*vsv.y;
        o.z = acc[d4].z*w1 + w2*vsv.z;
        o.w = acc[d4].w*w1 + w2*vsv.w;
        ((float4*)cp)[d4] = o;
    }
}

// ---------------------------------------------------------------------------
// Kernel 4: output projection. Out[row, e] = ctx[row,:] . Wo[e,:] + bo[e]
// ---------------------------------------------------------------------------
__global__ __launch_bounds__(256) void out_gemm(
    const float* __restrict__ A, const float* __restrict__ W,
    const float* __restrict__ bias, float* __restrict__ Out)
{
    __shared__ float As[64][68];
    __shared__ float Bs[64][68];
    const int row0 = blockIdx.y * 64, col0 = blockIdx.x * 64;
    const int tid = threadIdx.x;
    const int tx = tid & 15, ty = tid >> 4;
    const int lr = tid >> 4, lc = tid & 15;
    float acc[4][4] = {};
    for (int k0 = 0; k0 < 512; k0 += 64) {
        #pragma unroll
        for (int i = 0; i < 4; ++i) {
            int r = lr + i * 16;
            float4 xa = *(const float4*)&A[(size_t)(row0 + r) * 512 + k0 + lc * 4];
            As[lc*4+0][r] = xa.x; As[lc*4+1][r] = xa.y;
            As[lc*4+2][r] = xa.z; As[lc*4+3][r] = xa.w;
            float4 wb = *(const float4*)&W[(size_t)(col0 + r) * 512 + k0 + lc * 4];
            Bs[lc*4+0][r] = wb.x; Bs[lc*4+1][r] = wb.y;
            Bs[lc*4+2][r] = wb.z; Bs[lc*4+3][r] = wb.w;
        }
        __syncthreads();
        #pragma unroll
        for (int kk = 0; kk < 64; ++kk) {
            float4 a4 = *(const float4*)&As[kk][ty*4];
            float4 b4 = *(const float4*)&Bs[kk][tx*4];
            float av[4] = {a4.x, a4.y, a4.z, a4.w};
            float bw[4] = {b4.x, b4.y, b4.z, b4.w};
            #pragma unroll
            for (int i = 0; i < 4; ++i)
                #pragma unroll
                for (int j = 0; j < 4; ++j)
                    acc[i][j] += av[i] * bw[j];
        }
        __syncthreads();
    }
    #pragma unroll
    for (int i = 0; i < 4; ++i) {
        int grow = row0 + ty*4 + i;
        #pragma unroll
        for (int j = 0; j < 4; ++j) {
            int gcol = col0 + tx*4 + j;
            Out[(size_t)grow * 512 + gcol] = acc[i][j] + bias[gcol];
        }
    }
}

extern "C" void kernel_launch(void* const* d_in, const int* in_sizes, int n_in,
                              void* d_out, int out_size, void* d_ws, size_t ws_size,
                              hipStream_t stream)
{
    const float* x    = (const float*)d_in[0];
    const float* dock = (const float*)d_in[1];
    const int*   mask = (const int*)d_in[2];
    const float* Wq   = (const float*)d_in[3];
    const float* bq   = (const float*)d_in[4];
    const float* Wk   = (const float*)d_in[5];
    const float* bk   = (const float*)d_in[6];
    const float* Wv   = (const float*)d_in[7];
    const float* bv   = (const float*)d_in[8];
    const float* Wo   = (const float*)d_in[9];
    const float* bo   = (const float*)d_in[10];
    const float* beta = (const float*)d_in[12];   // alpha = d_in[11] unused
    float* out = (float*)d_out;

    char* ws = (char*)d_ws;
    const size_t nqkv = (size_t)B_ * H_ * S_ * HD_;   // 4,194,304 elements
    __hip_bfloat16* Qb = (__hip_bfloat16*)ws;
    __hip_bfloat16* Kb = Qb + nqkv;
    __hip_bfloat16* Vb = Kb + nqkv;
    float* Vsum = (float*)(ws + 3 * nqkv * sizeof(__hip_bfloat16));           // 8 KiB
    float* ctx  = (float*)(ws + 3 * nqkv * sizeof(__hip_bfloat16) + 8192);    // 16.8 MB

    qkv_gemm<<<dim3(8, 128, 3), 256, 0, stream>>>(x, Wq, bq, Wk, bk, Wv, bv, Qb, Kb, Vb);
    vsum_kernel<<<32, 256, 0, stream>>>(Vb, Vsum);
    attn_kernel<<<dim3(8, 32), 256, 0, stream>>>(Qb, Kb, Vb, Vsum, dock, mask, beta, ctx);
    out_gemm<<<dim3(8, 128), 256, 0, stream>>>(ctx, Wo, bo, out);
}

// Round 2
// 408.354 us; speedup vs baseline: 5.5869x; 5.5869x over previous
//
#include <hip/hip_runtime.h>
#include <hip/hip_bf16.h>

// Problem: B=4, S=2048, D=512, H=8, HD=64
#define B_ 4
#define S_ 2048
#define D_ 512
#define H_ 8
#define HD_ 64

typedef unsigned int uint;
typedef __attribute__((ext_vector_type(4))) float f32x4;
typedef __attribute__((ext_vector_type(8))) short bf16x8;

__device__ __forceinline__ float bflo(uint u){ union{uint i;float f;}c; c.i = u<<16;          return c.f; }
__device__ __forceinline__ float bfhi(uint u){ union{uint i;float f;}c; c.i = u & 0xffff0000u; return c.f; }
__device__ __forceinline__ float bf2f(unsigned short u){ union{uint i;float f;}c; c.i = (uint)u<<16; return c.f; }
__device__ __forceinline__ unsigned short f2bf(float f){
    __hip_bfloat16 h = __float2bfloat16(f);
    return *reinterpret_cast<unsigned short*>(&h);
}

// ---------------------------------------------------------------------------
// Kernel 1: fused QKV projection (fp32 VALU GEMM, unchanged structure).
// Q,K written (B,H,S,HD); V written TRANSPOSED (B,H,HD,S) for PV B-frags.
// ---------------------------------------------------------------------------
__global__ __launch_bounds__(256) void qkv_gemm(
    const float* __restrict__ x,
    const float* __restrict__ Wq, const float* __restrict__ bq,
    const float* __restrict__ Wk, const float* __restrict__ bk,
    const float* __restrict__ Wv, const float* __restrict__ bv,
    __hip_bfloat16* __restrict__ Qb, __hip_bfloat16* __restrict__ Kb,
    __hip_bfloat16* __restrict__ Vt)
{
    __shared__ float As[64][68];  // [k][m]
    __shared__ float Bs[64][68];  // [k][n]
    const int which = blockIdx.z;
    const float* W    = which==0 ? Wq : (which==1 ? Wk : Wv);
    const float* bias = which==0 ? bq : (which==1 ? bk : bv);
    __hip_bfloat16* Out = which==0 ? Qb : (which==1 ? Kb : Vt);

    const int row0 = blockIdx.y * 64;
    const int col0 = blockIdx.x * 64;
    const int tid = threadIdx.x;
    const int tx = tid & 15, ty = tid >> 4;
    const int lr = tid >> 4, lc = tid & 15;

    float acc[4][4] = {};
    for (int k0 = 0; k0 < 512; k0 += 64) {
        #pragma unroll
        for (int i = 0; i < 4; ++i) {
            int r = lr + i * 16;
            float4 xa = *(const float4*)&x[(size_t)(row0 + r) * 512 + k0 + lc * 4];
            As[lc*4+0][r] = xa.x; As[lc*4+1][r] = xa.y;
            As[lc*4+2][r] = xa.z; As[lc*4+3][r] = xa.w;
            float4 wb = *(const float4*)&W[(size_t)(col0 + r) * 512 + k0 + lc * 4];
            Bs[lc*4+0][r] = wb.x; Bs[lc*4+1][r] = wb.y;
            Bs[lc*4+2][r] = wb.z; Bs[lc*4+3][r] = wb.w;
        }
        __syncthreads();
        #pragma unroll
        for (int kk = 0; kk < 64; ++kk) {
            float4 a4 = *(const float4*)&As[kk][ty*4];
            float4 b4 = *(const float4*)&Bs[kk][tx*4];
            float av[4] = {a4.x, a4.y, a4.z, a4.w};
            float bw[4] = {b4.x, b4.y, b4.z, b4.w};
            #pragma unroll
            for (int i = 0; i < 4; ++i)
                #pragma unroll
                for (int j = 0; j < 4; ++j)
                    acc[i][j] += av[i] * bw[j];
        }
        __syncthreads();
    }
    #pragma unroll
    for (int i = 0; i < 4; ++i) {
        int grow = row0 + ty*4 + i;
        int b = grow >> 11, s = grow & 2047;
        #pragma unroll
        for (int j = 0; j < 4; ++j) {
            int gcol = col0 + tx*4 + j;
            float v = acc[i][j] + bias[gcol];
            int h = gcol >> 6, d = gcol & 63;
            if (which == 2) {
                // V transposed: Vt[b][h][d][s]
                Out[((size_t)(b*H_ + h) * HD_ + d) * S_ + s] = __float2bfloat16(v);
            } else {
                Out[(((size_t)(b*H_ + h) * S_ + s) << 6) + d] = __float2bfloat16(v);
            }
        }
    }
}

// ---------------------------------------------------------------------------
// Kernel 2: Vsum[b,h,d] = sum_s V[b,h,s,d] from Vt rows (coalesced).
// One wave per (bh,d) row. grid 512 x (4 rows/block)
// ---------------------------------------------------------------------------
__global__ __launch_bounds__(256) void vsum2(
    const __hip_bfloat16* __restrict__ Vt, float* __restrict__ Vsum)
{
    const int row = blockIdx.x * 4 + (threadIdx.x >> 6);   // 0..2047 = bh*64+d
    const int l = threadIdx.x & 63;
    const unsigned short* p = (const unsigned short*)Vt + (size_t)row * S_;
    float s = 0.f;
    #pragma unroll
    for (int i = 0; i < 4; ++i) {
        uint4 u = *(const uint4*)(p + i * 512 + l * 8);
        s += bf2f((unsigned short)(u.x & 0xffff)) + bf2f((unsigned short)(u.x >> 16));
        s += bf2f((unsigned short)(u.y & 0xffff)) + bf2f((unsigned short)(u.y >> 16));
        s += bf2f((unsigned short)(u.z & 0xffff)) + bf2f((unsigned short)(u.z >> 16));
        s += bf2f((unsigned short)(u.w & 0xffff)) + bf2f((unsigned short)(u.w >> 16));
    }
    #pragma unroll
    for (int m = 1; m < 64; m <<= 1) s += __shfl_xor(s, m);
    if (l == 0) Vsum[row] = s;
}

// ---------------------------------------------------------------------------
// Kernel 3: MFMA flash attention.
// 4 waves/block, 32 q-rows/wave (128 q/block). KV step = 64 keys.
// Swapped QK^T: sacc = mfma(Kfrag, Qfrag) -> D[key][q], q on lane&15.
// PV: cacc = mfma(Vtfrag, Pfrag) -> D[d][q], q stays on lane&15 (f, 1/l local).
// K frags & Vt frags read directly from global (L1/L2-resident).
// ---------------------------------------------------------------------------
__global__ __launch_bounds__(256, 2) void attn_mfma(
    const __hip_bfloat16* __restrict__ Qb, const __hip_bfloat16* __restrict__ Kb,
    const __hip_bfloat16* __restrict__ Vt, const float* __restrict__ Vsum,
    const float* __restrict__ dock, const int* __restrict__ mask,
    const float* __restrict__ beta_p, float* __restrict__ ctx)
{
    __shared__ float mbias[2048];                  // key-mask bias for this b
    __shared__ unsigned short Plds[4][32][72];     // per-wave P row-major [q][key]
    __shared__ float ctxl[4][32][68];              // per-wave epilogue transpose

    const int bh = blockIdx.y, b = bh >> 3, h = bh & 7;
    const int t = threadIdx.x, w = t >> 6, l = t & 63;
    const int g = l >> 4, c = l & 15;
    const int q0 = blockIdx.x * 128 + w * 32;
    const float beta = beta_p[0];

    for (int i = t; i < 2048; i += 256)
        mbias[i] = mask[b * S_ + i] ? 0.f : -1e30f;
    __syncthreads();

    // Q fragments, prescaled by 1/sqrt(HD)=0.125 (exact pow2 scale in bf16)
    bf16x8 qf[2][2];
    #pragma unroll
    for (int qt = 0; qt < 2; ++qt)
        #pragma unroll
        for (int ks = 0; ks < 2; ++ks) {
            const unsigned short* qp = (const unsigned short*)Qb +
                ((size_t)bh * S_ + q0 + qt * 16 + c) * HD_ + ks * 32 + g * 8;
            bf16x8 raw = *(const bf16x8*)qp;
            bf16x8 sc8;
            #pragma unroll
            for (int j = 0; j < 8; ++j) {
                float f = bf2f((unsigned short)raw[j]) * 0.125f;
                sc8[j] = (short)f2bf(f);
            }
            qf[qt][ks] = sc8;
        }

    f32x4 cacc[2][4];
    #pragma unroll
    for (int qt = 0; qt < 2; ++qt)
        #pragma unroll
        for (int dt = 0; dt < 4; ++dt) cacc[qt][dt] = (f32x4)0.f;
    float m_[2] = {-INFINITY, -INFINITY};
    float l_[2] = {0.f, 0.f};

    for (int k0 = 0; k0 < S_; k0 += 64) {
        // ---- QK^T (swapped): D[key][q] ----
        f32x4 sacc[2][4];
        #pragma unroll
        for (int qt = 0; qt < 2; ++qt)
            #pragma unroll
            for (int kt = 0; kt < 4; ++kt) sacc[qt][kt] = (f32x4)0.f;
        #pragma unroll
        for (int kt = 0; kt < 4; ++kt) {
            const unsigned short* kp = (const unsigned short*)Kb +
                ((size_t)bh * S_ + k0 + kt * 16 + c) * HD_ + g * 8;
            bf16x8 kf0 = *(const bf16x8*)kp;
            bf16x8 kf1 = *(const bf16x8*)(kp + 32);
            #pragma unroll
            for (int qt = 0; qt < 2; ++qt) {
                sacc[qt][kt] = __builtin_amdgcn_mfma_f32_16x16x32_bf16(kf0, qf[qt][0], sacc[qt][kt], 0, 0, 0);
                sacc[qt][kt] = __builtin_amdgcn_mfma_f32_16x16x32_bf16(kf1, qf[qt][1], sacc[qt][kt], 0, 0, 0);
            }
        }
        // per-lane mask bias: key = k0 + kt*16 + g*4 + r
        float mb[4][4];
        #pragma unroll
        for (int kt = 0; kt < 4; ++kt)
            #pragma unroll
            for (int r = 0; r < 4; ++r)
                mb[kt][r] = mbias[k0 + kt * 16 + g * 4 + r];

        // ---- online softmax per qt (q = q0 + 16qt + c) ----
        #pragma unroll
        for (int qt = 0; qt < 2; ++qt) {
            float sc[16];
            float vmax = -INFINITY;
            #pragma unroll
            for (int kt = 0; kt < 4; ++kt)
                #pragma unroll
                for (int r = 0; r < 4; ++r) {
                    float v = sacc[qt][kt][r] + mb[kt][r];
                    sc[kt * 4 + r] = v;
                    vmax = fmaxf(vmax, v);
                }
            vmax = fmaxf(vmax, __shfl_xor(vmax, 16));
            vmax = fmaxf(vmax, __shfl_xor(vmax, 32));
            float mnew = fmaxf(m_[qt], vmax);
            float f = __expf(m_[qt] - mnew);
            float p[16], psum = 0.f;
            #pragma unroll
            for (int i = 0; i < 16; ++i) { p[i] = __expf(sc[i] - mnew); psum += p[i]; }
            psum += __shfl_xor(psum, 16);
            psum += __shfl_xor(psum, 32);
            l_[qt] = l_[qt] * f + psum;
            m_[qt] = mnew;
            #pragma unroll
            for (int dt = 0; dt < 4; ++dt) cacc[qt][dt] *= f;
            // write P row q_local = 16qt + c, keys kt*16 + g*4 .. +3 (b64)
            #pragma unroll
            for (int kt = 0; kt < 4; ++kt) {
                uint lo = (uint)f2bf(p[kt * 4 + 0]) | ((uint)f2bf(p[kt * 4 + 1]) << 16);
                uint hi = (uint)f2bf(p[kt * 4 + 2]) | ((uint)f2bf(p[kt * 4 + 3]) << 16);
                *(uint2*)&Plds[w][16 * qt + c][kt * 16 + g * 4] = make_uint2(lo, hi);
            }
        }
        // in-wave cross-lane LDS visibility: drain DS queue, block reordering
        asm volatile("s_waitcnt lgkmcnt(0)" ::: "memory");
        __builtin_amdgcn_sched_barrier(0);

        // ---- PV: cacc[qt][dt] += mfma(Vt-frag, P-frag) -> D[d][q] ----
        bf16x8 pf[2][2];
        #pragma unroll
        for (int qt = 0; qt < 2; ++qt)
            #pragma unroll
            for (int ks = 0; ks < 2; ++ks)
                pf[qt][ks] = *(const bf16x8*)&Plds[w][16 * qt + c][ks * 32 + g * 8];
        #pragma unroll
        for (int dt = 0; dt < 4; ++dt) {
            const unsigned short* vp = (const unsigned short*)Vt +
                ((size_t)bh * HD_ + dt * 16 + c) * S_ + k0 + g * 8;
            bf16x8 vf0 = *(const bf16x8*)vp;
            bf16x8 vf1 = *(const bf16x8*)(vp + 32);
            #pragma unroll
            for (int qt = 0; qt < 2; ++qt) {
                cacc[qt][dt] = __builtin_amdgcn_mfma_f32_16x16x32_bf16(vf0, pf[qt][0], cacc[qt][dt], 0, 0, 0);
                cacc[qt][dt] = __builtin_amdgcn_mfma_f32_16x16x32_bf16(vf1, pf[qt][1], cacc[qt][dt], 0, 0, 0);
            }
        }
    }

    // ---- epilogue: blend + transpose via LDS, coalesced f32 writes ----
    #pragma unroll
    for (int qt = 0; qt < 2; ++qt) {
        int qg = q0 + 16 * qt + c;
        float w1 = (1.f - beta) / l_[qt];
        float dq = (mask[b * S_ + qg] ? dock[b * S_ + qg] : 0.f) * beta;
        #pragma unroll
        for (int dt = 0; dt < 4; ++dt)
            #pragma unroll
            for (int r = 0; r < 4; ++r) {
                int d = dt * 16 + g * 4 + r;
                ctxl[w][16 * qt + c][d] = cacc[qt][dt][r] * w1 + dq * Vsum[bh * 64 + d];
            }
    }
    asm volatile("s_waitcnt lgkmcnt(0)" ::: "memory");
    __builtin_amdgcn_sched_barrier(0);
    {
        const int qloc = l >> 1, half = l & 1;
        const int qg = q0 + qloc;
        float* cp = ctx + ((size_t)(b * S_ + qg)) * D_ + h * HD_ + half * 32;
        #pragma unroll
        for (int j = 0; j < 8; ++j) {
            float4 v = *(const float4*)&ctxl[w][qloc][half * 32 + j * 4];
            ((float4*)cp)[j] = v;
        }
    }
}

// ---------------------------------------------------------------------------
// Kernel 4: output projection (fp32 VALU GEMM, unchanged).
// ---------------------------------------------------------------------------
__global__ __launch_bounds__(256) void out_gemm(
    const float* __restrict__ A, const float* __restrict__ W,
    const float* __restrict__ bias, float* __restrict__ Out)
{
    __shared__ float As[64][68];
    __shared__ float Bs[64][68];
    const int row0 = blockIdx.y * 64, col0 = blockIdx.x * 64;
    const int tid = threadIdx.x;
    const int tx = tid & 15, ty = tid >> 4;
    const int lr = tid >> 4, lc = tid & 15;
    float acc[4][4] = {};
    for (int k0 = 0; k0 < 512; k0 += 64) {
        #pragma unroll
        for (int i = 0; i < 4; ++i) {
            int r = lr + i * 16;
            float4 xa = *(const float4*)&A[(size_t)(row0 + r) * 512 + k0 + lc * 4];
            As[lc*4+0][r] = xa.x; As[lc*4+1][r] = xa.y;
            As[lc*4+2][r] = xa.z; As[lc*4+3][r] = xa.w;
            float4 wb = *(const float4*)&W[(size_t)(col0 + r) * 512 + k0 + lc * 4];
            Bs[lc*4+0][r] = wb.x; Bs[lc*4+1][r] = wb.y;
            Bs[lc*4+2][r] = wb.z; Bs[lc*4+3][r] = wb.w;
        }
        __syncthreads();
        #pragma unroll
        for (int kk = 0; kk < 64; ++kk) {
            float4 a4 = *(const float4*)&As[kk][ty*4];
            float4 b4 = *(const float4*)&Bs[kk][tx*4];
            float av[4] = {a4.x, a4.y, a4.z, a4.w};
            float bw[4] = {b4.x, b4.y, b4.z, b4.w};
            #pragma unroll
            for (int i = 0; i < 4; ++i)
                #pragma unroll
                for (int j = 0; j < 4; ++j)
                    acc[i][j] += av[i] * bw[j];
        }
        __syncthreads();
    }
    #pragma unroll
    for (int i = 0; i < 4; ++i) {
        int grow = row0 + ty*4 + i;
        #pragma unroll
        for (int j = 0; j < 4; ++j) {
            int gcol = col0 + tx*4 + j;
            Out[(size_t)grow * 512 + gcol] = acc[i][j] + bias[gcol];
        }
    }
}

extern "C" void kernel_launch(void* const* d_in, const int* in_sizes, int n_in,
                              void* d_out, int out_size, void* d_ws, size_t ws_size,
                              hipStream_t stream)
{
    const float* x    = (const float*)d_in[0];
    const float* dock = (const float*)d_in[1];
    const int*   mask = (const int*)d_in[2];
    const float* Wq   = (const float*)d_in[3];
    const float* bq   = (const float*)d_in[4];
    const float* Wk   = (const float*)d_in[5];
    const float* bk   = (const float*)d_in[6];
    const float* Wv   = (const float*)d_in[7];
    const float* bv   = (const float*)d_in[8];
    const float* Wo   = (const float*)d_in[9];
    const float* bo   = (const float*)d_in[10];
    const float* beta = (const float*)d_in[12];   // alpha = d_in[11] unused
    float* out = (float*)d_out;

    char* ws = (char*)d_ws;
    const size_t nqkv = (size_t)B_ * H_ * S_ * HD_;           // 4,194,304 elems
    __hip_bfloat16* Qb = (__hip_bfloat16*)ws;                 // 8 MB
    __hip_bfloat16* Kb = Qb + nqkv;                           // 8 MB
    __hip_bfloat16* Vt = Kb + nqkv;                           // 8 MB (B,H,HD,S)
    float* Vsum = (float*)(ws + 3 * nqkv * sizeof(__hip_bfloat16));        // 8 KB
    float* ctx  = (float*)(ws + 3 * nqkv * sizeof(__hip_bfloat16) + 8192); // 16.8 MB

    qkv_gemm<<<dim3(8, 128, 3), 256, 0, stream>>>(x, Wq, bq, Wk, bk, Wv, bv, Qb, Kb, Vt);
    vsum2<<<512, 256, 0, stream>>>(Vt, Vsum);
    attn_mfma<<<dim3(16, 32), 256, 0, stream>>>(Qb, Kb, Vt, Vsum, dock, mask, beta, ctx);
    out_gemm<<<dim3(8, 128), 256, 0, stream>>>(ctx, Wo, bo, out);
}

// Round 3
// 175.685 us; speedup vs baseline: 12.9858x; 2.3243x over previous
//
#include <hip/hip_runtime.h>
#include <hip/hip_bf16.h>

// Problem: B=4, S=2048, D=512, H=8, HD=64
#define B_ 4
#define S_ 2048
#define D_ 512
#define H_ 8
#define HD_ 64

typedef unsigned int uint;
typedef unsigned short ushort_t;
typedef __attribute__((ext_vector_type(4))) float f32x4;
typedef __attribute__((ext_vector_type(8))) short bf16x8;

__device__ __forceinline__ float bf2f(unsigned short u){ union{uint i;float f;}c; c.i = (uint)u<<16; return c.f; }
__device__ __forceinline__ unsigned short f2bf(float f){
    __hip_bfloat16 h = __float2bfloat16(f);
    return *reinterpret_cast<unsigned short*>(&h);
}

__device__ __forceinline__ void gload16(const unsigned short* g, unsigned short* l){
    __builtin_amdgcn_global_load_lds(
        (const __attribute__((address_space(1))) unsigned int*)g,
        (__attribute__((address_space(3))) unsigned int*)l, 16, 0, 0);
}

// ---------------------------------------------------------------------------
// Kernel 0: fp32 -> bf16 conversion of x, stacked [Wq;Wk;Wv], and Wo.
// ---------------------------------------------------------------------------
__global__ __launch_bounds__(256) void convert_all(
    const float* __restrict__ x,
    const float* __restrict__ Wq, const float* __restrict__ Wk,
    const float* __restrict__ Wv, const float* __restrict__ Wo,
    ushort_t* __restrict__ xb, ushort_t* __restrict__ Wqkvb, ushort_t* __restrict__ Wob)
{
    const int NX = 1048576;            // x in float4 units (8192*512/4)
    const int NW = 65536;              // one W in float4 units
    const int total = NX + 4 * NW;     // 1310720
    for (int i = blockIdx.x * 256 + threadIdx.x; i < total; i += gridDim.x * 256) {
        const float* src; ushort_t* dst; int so, dofs;
        if (i < NX) { src = x; so = i; dst = xb; dofs = i; }
        else if (i < NX + 3 * NW) {
            int j = i - NX;
            if (j < NW)          { src = Wq; so = j; }
            else if (j < 2 * NW) { src = Wk; so = j - NW; }
            else                 { src = Wv; so = j - 2 * NW; }
            dst = Wqkvb; dofs = j;
        } else { int k = i - NX - 3 * NW; src = Wo; so = k; dst = Wob; dofs = k; }
        float4 v = ((const float4*)src)[so];
        ushort4 u;
        u.x = f2bf(v.x); u.y = f2bf(v.y); u.z = f2bf(v.z); u.w = f2bf(v.w);
        ((ushort4*)dst)[dofs] = u;
    }
}

// ---------------------------------------------------------------------------
// bf16 MFMA GEMM, m97 structure: 128x128 tile, BK=64, global_load_lds w=16,
// both-sides XOR swizzle (slot ^= row&7). C[m,n] = sum_k A[m,k]*B[n,k].
// MODE 0: QKV (N=1536). Q/K -> (B,H,S,HD) bf16; V -> Vt (B,H,HD,S) bf16,
//         all via LDS retile for coalesced 128B stores.
// MODE 1: OUT (N=512). f32 scalar stores + bias.
// ---------------------------------------------------------------------------
template<int MODE>
__global__ __launch_bounds__(256) void gemm_mfma(
    const ushort_t* __restrict__ A, const ushort_t* __restrict__ Bw,
    const float* __restrict__ b0, const float* __restrict__ b1, const float* __restrict__ b2,
    ushort_t* __restrict__ O0, ushort_t* __restrict__ O1, ushort_t* __restrict__ O2,
    float* __restrict__ Of)
{
    __shared__ __align__(16) unsigned char smem[34816];
    ushort_t* sA = (ushort_t*)smem;          // [128][64]
    ushort_t* sB = sA + 8192;                // [128][64]

    const int t = threadIdx.x, w = t >> 6, l = t & 63, g = l >> 4, c = l & 15;
    const int wm = w >> 1, wn = w & 1;
    const int row0 = blockIdx.y * 128, col0 = blockIdx.x * 128;

    // staging: source addresses pre-swizzled so linear LDS + XOR-read is correct
    const ushort_t* aSrc[4]; const ushort_t* bSrc[4];
    ushort_t* aDst[4]; ushort_t* bDst[4];
    #pragma unroll
    for (int i = 0; i < 4; ++i) {
        int cc = i * 256 + t;
        int row = cc >> 3, slot = (cc & 7) ^ (row & 7);
        aSrc[i] = A  + (size_t)(row0 + row) * 512 + slot * 8;
        bSrc[i] = Bw + (size_t)(col0 + row) * 512 + slot * 8;
        aDst[i] = sA + (i * 256 + w * 64) * 8;
        bDst[i] = sB + (i * 256 + w * 64) * 8;
    }

    f32x4 acc[4][4];
    #pragma unroll
    for (int mi = 0; mi < 4; ++mi)
        #pragma unroll
        for (int ni = 0; ni < 4; ++ni) acc[mi][ni] = (f32x4)0.f;

    for (int ks = 0; ks < 8; ++ks) {
        #pragma unroll
        for (int i = 0; i < 4; ++i) {
            gload16(aSrc[i], aDst[i]);
            gload16(bSrc[i], bDst[i]);
        }
        __syncthreads();
        #pragma unroll
        for (int kh = 0; kh < 2; ++kh) {
            bf16x8 af[4], bfv[4];
            const int sw = (((kh << 2) | g) ^ (c & 7)) << 3;
            #pragma unroll
            for (int mi = 0; mi < 4; ++mi)
                af[mi] = *(const bf16x8*)&sA[(wm * 64 + mi * 16 + c) * 64 + sw];
            #pragma unroll
            for (int ni = 0; ni < 4; ++ni)
                bfv[ni] = *(const bf16x8*)&sB[(wn * 64 + ni * 16 + c) * 64 + sw];
            #pragma unroll
            for (int mi = 0; mi < 4; ++mi)
                #pragma unroll
                for (int ni = 0; ni < 4; ++ni)
                    acc[mi][ni] = __builtin_amdgcn_mfma_f32_16x16x32_bf16(af[mi], bfv[ni], acc[mi][ni], 0, 0, 0);
        }
        #pragma unroll
        for (int i = 0; i < 4; ++i) { aSrc[i] += 64; bSrc[i] += 64; }
        __syncthreads();
    }

    if (MODE == 1) {
        #pragma unroll
        for (int mi = 0; mi < 4; ++mi)
            #pragma unroll
            for (int ni = 0; ni < 4; ++ni) {
                int n = col0 + wn * 64 + ni * 16 + c;
                float bias = b0[n];
                #pragma unroll
                for (int r = 0; r < 4; ++r)
                    Of[(size_t)(row0 + wm * 64 + mi * 16 + 4 * g + r) * 512 + n] =
                        acc[mi][ni][r] + bias;
            }
    } else {
        const int which = col0 >> 9;   // 0=Q 1=K 2=V (128-tiles never straddle)
        const float* bias = which == 0 ? b0 : (which == 1 ? b1 : b2);
        ushort_t (*Cl)[136] = (ushort_t(*)[136])smem;
        if (which < 2) {
            #pragma unroll
            for (int mi = 0; mi < 4; ++mi)
                #pragma unroll
                for (int ni = 0; ni < 4; ++ni) {
                    int n = wn * 64 + ni * 16 + c;
                    float bb = bias[(col0 & 511) + n];
                    #pragma unroll
                    for (int r = 0; r < 4; ++r)
                        Cl[wm * 64 + mi * 16 + 4 * g + r][n] = f2bf(acc[mi][ni][r] + bb);
                }
        } else {
            #pragma unroll
            for (int mi = 0; mi < 4; ++mi)
                #pragma unroll
                for (int ni = 0; ni < 4; ++ni) {
                    int n = wn * 64 + ni * 16 + c;
                    float bb = bias[(col0 & 511) + n];
                    #pragma unroll
                    for (int r = 0; r < 4; ++r)
                        Cl[n][wm * 64 + mi * 16 + 4 * g + r] = f2bf(acc[mi][ni][r] + bb);
                }
        }
        __syncthreads();
        const int r = t >> 1, half = t & 1;
        const int b = row0 >> 11;
        if (which < 2) {
            ushort_t* Out = which == 0 ? O0 : O1;
            int s = (row0 & 2047) + r;
            int e = (col0 & 511) + half * 64;
            int h = e >> 6;
            ushort_t* dst = Out + (((size_t)(b * 8 + h) * 2048 + s) << 6);
            #pragma unroll
            for (int j = 0; j < 8; ++j)
                *(bf16x8*)(dst + j * 8) = *(const bf16x8*)&Cl[r][half * 64 + j * 8];
        } else {
            int e = (col0 & 511) + r;
            int h = e >> 6, d = e & 63;
            int s0 = (row0 & 2047) + half * 64;
            ushort_t* dst = O2 + ((size_t)(b * 8 + h) * 64 + d) * 2048 + s0;
            #pragma unroll
            for (int j = 0; j < 8; ++j)
                *(bf16x8*)(dst + j * 8) = *(const bf16x8*)&Cl[r][half * 64 + j * 8];
        }
    }
}

// ---------------------------------------------------------------------------
// Vsum[b,h,d] = sum_s V[b,h,s,d] from Vt rows (coalesced).
// ---------------------------------------------------------------------------
__global__ __launch_bounds__(256) void vsum2(
    const __hip_bfloat16* __restrict__ Vt, float* __restrict__ Vsum)
{
    const int row = blockIdx.x * 4 + (threadIdx.x >> 6);   // 0..2047 = bh*64+d
    const int l = threadIdx.x & 63;
    const unsigned short* p = (const unsigned short*)Vt + (size_t)row * S_;
    float s = 0.f;
    #pragma unroll
    for (int i = 0; i < 4; ++i) {
        uint4 u = *(const uint4*)(p + i * 512 + l * 8);
        s += bf2f((unsigned short)(u.x & 0xffff)) + bf2f((unsigned short)(u.x >> 16));
        s += bf2f((unsigned short)(u.y & 0xffff)) + bf2f((unsigned short)(u.y >> 16));
        s += bf2f((unsigned short)(u.z & 0xffff)) + bf2f((unsigned short)(u.z >> 16));
        s += bf2f((unsigned short)(u.w & 0xffff)) + bf2f((unsigned short)(u.w >> 16));
    }
    #pragma unroll
    for (int m = 1; m < 64; m <<= 1) s += __shfl_xor(s, m);
    if (l == 0) Vsum[row] = s;
}

// ---------------------------------------------------------------------------
// MFMA flash attention (unchanged math); epilogue now writes bf16 ctx.
// ---------------------------------------------------------------------------
__global__ __launch_bounds__(256, 2) void attn_mfma(
    const __hip_bfloat16* __restrict__ Qb, const __hip_bfloat16* __restrict__ Kb,
    const __hip_bfloat16* __restrict__ Vt, const float* __restrict__ Vsum,
    const float* __restrict__ dock, const int* __restrict__ mask,
    const float* __restrict__ beta_p, ushort_t* __restrict__ ctxb)
{
    __shared__ float mbias[2048];
    __shared__ unsigned short Plds[4][32][72];
    __shared__ float ctxl[4][32][68];

    const int bh = blockIdx.y, b = bh >> 3, h = bh & 7;
    const int t = threadIdx.x, w = t >> 6, l = t & 63;
    const int g = l >> 4, c = l & 15;
    const int q0 = blockIdx.x * 128 + w * 32;
    const float beta = beta_p[0];

    for (int i = t; i < 2048; i += 256)
        mbias[i] = mask[b * S_ + i] ? 0.f : -1e30f;
    __syncthreads();

    bf16x8 qf[2][2];
    #pragma unroll
    for (int qt = 0; qt < 2; ++qt)
        #pragma unroll
        for (int ks = 0; ks < 2; ++ks) {
            const unsigned short* qp = (const unsigned short*)Qb +
                ((size_t)bh * S_ + q0 + qt * 16 + c) * HD_ + ks * 32 + g * 8;
            bf16x8 raw = *(const bf16x8*)qp;
            bf16x8 sc8;
            #pragma unroll
            for (int j = 0; j < 8; ++j) {
                float f = bf2f((unsigned short)raw[j]) * 0.125f;
                sc8[j] = (short)f2bf(f);
            }
            qf[qt][ks] = sc8;
        }

    f32x4 cacc[2][4];
    #pragma unroll
    for (int qt = 0; qt < 2; ++qt)
        #pragma unroll
        for (int dt = 0; dt < 4; ++dt) cacc[qt][dt] = (f32x4)0.f;
    float m_[2] = {-INFINITY, -INFINITY};
    float l_[2] = {0.f, 0.f};

    for (int k0 = 0; k0 < S_; k0 += 64) {
        f32x4 sacc[2][4];
        #pragma unroll
        for (int qt = 0; qt < 2; ++qt)
            #pragma unroll
            for (int kt = 0; kt < 4; ++kt) sacc[qt][kt] = (f32x4)0.f;
        #pragma unroll
        for (int kt = 0; kt < 4; ++kt) {
            const unsigned short* kp = (const unsigned short*)Kb +
                ((size_t)bh * S_ + k0 + kt * 16 + c) * HD_ + g * 8;
            bf16x8 kf0 = *(const bf16x8*)kp;
            bf16x8 kf1 = *(const bf16x8*)(kp + 32);
            #pragma unroll
            for (int qt = 0; qt < 2; ++qt) {
                sacc[qt][kt] = __builtin_amdgcn_mfma_f32_16x16x32_bf16(kf0, qf[qt][0], sacc[qt][kt], 0, 0, 0);
                sacc[qt][kt] = __builtin_amdgcn_mfma_f32_16x16x32_bf16(kf1, qf[qt][1], sacc[qt][kt], 0, 0, 0);
            }
        }
        float mb[4][4];
        #pragma unroll
        for (int kt = 0; kt < 4; ++kt)
            #pragma unroll
            for (int r = 0; r < 4; ++r)
                mb[kt][r] = mbias[k0 + kt * 16 + g * 4 + r];

        #pragma unroll
        for (int qt = 0; qt < 2; ++qt) {
            float sc[16];
            float vmax = -INFINITY;
            #pragma unroll
            for (int kt = 0; kt < 4; ++kt)
                #pragma unroll
                for (int r = 0; r < 4; ++r) {
                    float v = sacc[qt][kt][r] + mb[kt][r];
                    sc[kt * 4 + r] = v;
                    vmax = fmaxf(vmax, v);
                }
            vmax = fmaxf(vmax, __shfl_xor(vmax, 16));
            vmax = fmaxf(vmax, __shfl_xor(vmax, 32));
            float mnew = fmaxf(m_[qt], vmax);
            float f = __expf(m_[qt] - mnew);
            float p[16], psum = 0.f;
            #pragma unroll
            for (int i = 0; i < 16; ++i) { p[i] = __expf(sc[i] - mnew); psum += p[i]; }
            psum += __shfl_xor(psum, 16);
            psum += __shfl_xor(psum, 32);
            l_[qt] = l_[qt] * f + psum;
            m_[qt] = mnew;
            #pragma unroll
            for (int dt = 0; dt < 4; ++dt) cacc[qt][dt] *= f;
            #pragma unroll
            for (int kt = 0; kt < 4; ++kt) {
                uint lo = (uint)f2bf(p[kt * 4 + 0]) | ((uint)f2bf(p[kt * 4 + 1]) << 16);
                uint hi = (uint)f2bf(p[kt * 4 + 2]) | ((uint)f2bf(p[kt * 4 + 3]) << 16);
                *(uint2*)&Plds[w][16 * qt + c][kt * 16 + g * 4] = make_uint2(lo, hi);
            }
        }
        asm volatile("s_waitcnt lgkmcnt(0)" ::: "memory");
        __builtin_amdgcn_sched_barrier(0);

        bf16x8 pf[2][2];
        #pragma unroll
        for (int qt = 0; qt < 2; ++qt)
            #pragma unroll
            for (int ks = 0; ks < 2; ++ks)
                pf[qt][ks] = *(const bf16x8*)&Plds[w][16 * qt + c][ks * 32 + g * 8];
        #pragma unroll
        for (int dt = 0; dt < 4; ++dt) {
            const unsigned short* vp = (const unsigned short*)Vt +
                ((size_t)bh * HD_ + dt * 16 + c) * S_ + k0 + g * 8;
            bf16x8 vf0 = *(const bf16x8*)vp;
            bf16x8 vf1 = *(const bf16x8*)(vp + 32);
            #pragma unroll
            for (int qt = 0; qt < 2; ++qt) {
                cacc[qt][dt] = __builtin_amdgcn_mfma_f32_16x16x32_bf16(vf0, pf[qt][0], cacc[qt][dt], 0, 0, 0);
                cacc[qt][dt] = __builtin_amdgcn_mfma_f32_16x16x32_bf16(vf1, pf[qt][1], cacc[qt][dt], 0, 0, 0);
            }
        }
    }

    #pragma unroll
    for (int qt = 0; qt < 2; ++qt) {
        int qg = q0 + 16 * qt + c;
        float w1 = (1.f - beta) / l_[qt];
        float dq = (mask[b * S_ + qg] ? dock[b * S_ + qg] : 0.f) * beta;
        #pragma unroll
        for (int dt = 0; dt < 4; ++dt)
            #pragma unroll
            for (int r = 0; r < 4; ++r) {
                int d = dt * 16 + g * 4 + r;
                ctxl[w][16 * qt + c][d] = cacc[qt][dt][r] * w1 + dq * Vsum[bh * 64 + d];
            }
    }
    asm volatile("s_waitcnt lgkmcnt(0)" ::: "memory");
    __builtin_amdgcn_sched_barrier(0);
    {
        const int qloc = l >> 1, half = l & 1;
        const int qg = q0 + qloc;
        ushort_t* cp = ctxb + ((size_t)(b * 2048 + qg)) * 512 + h * 64 + half * 32;
        #pragma unroll
        for (int j = 0; j < 4; ++j) {
            float4 v0 = *(const float4*)&ctxl[w][qloc][half * 32 + j * 8];
            float4 v1 = *(const float4*)&ctxl[w][qloc][half * 32 + j * 8 + 4];
            bf16x8 u;
            u[0] = (short)f2bf(v0.x); u[1] = (short)f2bf(v0.y);
            u[2] = (short)f2bf(v0.z); u[3] = (short)f2bf(v0.w);
            u[4] = (short)f2bf(v1.x); u[5] = (short)f2bf(v1.y);
            u[6] = (short)f2bf(v1.z); u[7] = (short)f2bf(v1.w);
            *(bf16x8*)(cp + j * 8) = u;
        }
    }
}

extern "C" void kernel_launch(void* const* d_in, const int* in_sizes, int n_in,
                              void* d_out, int out_size, void* d_ws, size_t ws_size,
                              hipStream_t stream)
{
    const float* x    = (const float*)d_in[0];
    const float* dock = (const float*)d_in[1];
    const int*   mask = (const int*)d_in[2];
    const float* Wq   = (const float*)d_in[3];
    const float* bq   = (const float*)d_in[4];
    const float* Wk   = (const float*)d_in[5];
    const float* bk   = (const float*)d_in[6];
    const float* Wv   = (const float*)d_in[7];
    const float* bv   = (const float*)d_in[8];
    const float* Wo   = (const float*)d_in[9];
    const float* bo   = (const float*)d_in[10];
    const float* beta = (const float*)d_in[12];   // alpha = d_in[11] unused
    float* out = (float*)d_out;

    const size_t nqkv = (size_t)B_ * H_ * S_ * HD_;   // 4,194,304 elems
    ushort_t* xb    = (ushort_t*)d_ws;                // 8 MB (reused as ctxb)
    ushort_t* Qb    = xb + nqkv;                      // 8 MB
    ushort_t* Kb    = Qb + nqkv;                      // 8 MB
    ushort_t* Vt    = Kb + nqkv;                      // 8 MB (B,H,HD,S)
    ushort_t* Wqkvb = Vt + nqkv;                      // 1.5 MB  [1536][512]
    ushort_t* Wob   = Wqkvb + 1536 * 512;             // 0.5 MB  [512][512]
    float*    Vsum  = (float*)(Wob + 512 * 512);      // 8 KB
    ushort_t* ctxb  = xb;                             // alias (x consumed by then)

    convert_all<<<1280, 256, 0, stream>>>(x, Wq, Wk, Wv, Wo, xb, Wqkvb, Wob);
    gemm_mfma<0><<<dim3(12, 64), 256, 0, stream>>>(xb, Wqkvb, bq, bk, bv, Qb, Kb, Vt, nullptr);
    vsum2<<<512, 256, 0, stream>>>((const __hip_bfloat16*)Vt, Vsum);
    attn_mfma<<<dim3(16, 32), 256, 0, stream>>>(
        (const __hip_bfloat16*)Qb, (const __hip_bfloat16*)Kb, (const __hip_bfloat16*)Vt,
        Vsum, dock, mask, beta, ctxb);
    gemm_mfma<1><<<dim3(4, 64), 256, 0, stream>>>(ctxb, Wob, bo, nullptr, nullptr,
                                                  nullptr, nullptr, nullptr, out);
}